// Round 9
// baseline (508.965 us; speedup 1.0000x reference)
//
#include <hip/hip_runtime.h>
#include <stdint.h>

typedef int   v4i __attribute__((ext_vector_type(4)));
typedef float v4f __attribute__((ext_vector_type(4)));

#define TOK_M 8192   // B*S = 4*2048
#define DIM_K 4096   // IN
#define DIM_N 4096   // OUT

#define GL(src, dst)                                                                   \
  __builtin_amdgcn_global_load_lds((const __attribute__((address_space(1))) void*)(src), \
                                   (__attribute__((address_space(3))) void*)(dst), 16, 0, 0)

// ---------------------------------------------------------------------------
// Kernel 1: weight int32 -> int8 pack + per-row sums (fully coalesced)
// ---------------------------------------------------------------------------
__global__ __launch_bounds__(256) void k_pack_w(const int* __restrict__ w,
                                                int8_t* __restrict__ wq,
                                                float* __restrict__ wsumf) {
    __shared__ int sred[4];
    const int row = blockIdx.x;
    const int tid = threadIdx.x;
    const int4* src = (const int4*)(w + (size_t)row * DIM_K);
    unsigned* dst = (unsigned*)(wq + (size_t)row * DIM_K);
    int sum = 0;
#pragma unroll
    for (int c = 0; c < 4; ++c) {
        int4 iv = src[c * 256 + tid];
        sum += iv.x + iv.y + iv.z + iv.w;
        unsigned p = (unsigned)(iv.x & 255) | ((unsigned)(iv.y & 255) << 8) |
                     ((unsigned)(iv.z & 255) << 16) | ((unsigned)(iv.w & 255) << 24);
        dst[c * 256 + tid] = p;
    }
#pragma unroll
    for (int off = 32; off; off >>= 1) sum += __shfl_xor(sum, off);
    if ((tid & 63) == 0) sred[tid >> 6] = sum;
    __syncthreads();
    if (tid == 0) wsumf[row] = (float)(sred[0] + sred[1] + sred[2] + sred[3]);
}

// ---------------------------------------------------------------------------
// Kernel 2: per-token dynamic quant (coalesced chunked layout)
// ---------------------------------------------------------------------------
__global__ __launch_bounds__(256) void k_quant(const float* __restrict__ x,
                                               int8_t* __restrict__ q,
                                               float* __restrict__ sA,
                                               float* __restrict__ sB,
                                               float* __restrict__ sC) {
    __shared__ float redf[8];
    __shared__ int   redi[4];
    __shared__ float bcast[2];
    const int tok = blockIdx.x;
    const int tid = threadIdx.x;
    const v4f* xr = (const v4f*)(x + (size_t)tok * DIM_K);
    v4f v[4];
    float mn = 0.0f, mx = 0.0f;
#pragma unroll
    for (int c = 0; c < 4; ++c) {
        v[c] = xr[c * 256 + tid];
#pragma unroll
        for (int j = 0; j < 4; ++j) {
            mn = fminf(mn, v[c][j]);
            mx = fmaxf(mx, v[c][j]);
        }
    }
#pragma unroll
    for (int off = 32; off; off >>= 1) {
        mn = fminf(mn, __shfl_xor(mn, off));
        mx = fmaxf(mx, __shfl_xor(mx, off));
    }
    const int wid = tid >> 6;
    if ((tid & 63) == 0) { redf[wid] = mn; redf[4 + wid] = mx; }
    __syncthreads();
    if (tid == 0) {
        float m0 = fminf(fminf(redf[0], redf[1]), fminf(redf[2], redf[3]));
        float m1 = fmaxf(fmaxf(redf[4], redf[5]), fmaxf(redf[6], redf[7]));
        float scale = fmaxf((m1 - m0) / 255.0f, 1.1920928955078125e-07f);
        float zpf = -128.0f - rintf(m0 / scale);
        zpf = fminf(fmaxf(zpf, -128.0f), 127.0f);
        bcast[0] = scale; bcast[1] = zpf;
    }
    __syncthreads();
    const float scale = bcast[0];
    const float zpf   = bcast[1];
    const float inv   = 1.0f / scale;
    int qs = 0;
    unsigned* qo = (unsigned*)(q + (size_t)tok * DIM_K);
#pragma unroll
    for (int c = 0; c < 4; ++c) {
        unsigned p = 0;
#pragma unroll
        for (int j = 0; j < 4; ++j) {
            float qf = rintf(v[c][j] * inv) + zpf;
            qf = fminf(fmaxf(qf, -128.0f), 127.0f);
            int qi = (int)qf;
            qs += qi;
            p |= ((unsigned)(qi & 255)) << (8 * j);
        }
        qo[c * 256 + tid] = p;
    }
#pragma unroll
    for (int off = 32; off; off >>= 1) qs += __shfl_xor(qs, off);
    if ((tid & 63) == 0) redi[wid] = qs;
    __syncthreads();
    if (tid == 0) {
        int qtot = redi[0] + redi[1] + redi[2] + redi[3];
        sA[tok] = scale;
        sB[tok] = scale * zpf;
        sC[tok] = scale * ((float)qtot - 4096.0f * zpf);
    }
}

// ---------------------------------------------------------------------------
// Kernel 3: int8 GEMM 256x256 tile, 4 waves (2x2), per-wave 128x128,
// 16x16x64 MFMA, BK=64, triple-buffer 96KB, one barrier/tile, vmcnt(8).
// reads:mfma = 16:64 per wave -> LDS pipe at 59% of MFMA pipe.
// ---------------------------------------------------------------------------
__global__ __launch_bounds__(256, 1) void k_gemm(const int8_t* __restrict__ A,
                                                 const int8_t* __restrict__ B,
                                                 const float* __restrict__ sA,
                                                 const float* __restrict__ sB,
                                                 const float* __restrict__ sC,
                                                 const float* __restrict__ wsumf,
                                                 const float* __restrict__ scales,
                                                 const float* __restrict__ zeros,
                                                 float* __restrict__ out) {
    extern __shared__ int8_t lds[];   // 3 bufs x (A 16KB + B 16KB) = 96 KB
    const int tid = threadIdx.x;
    const int l = tid & 63;
    const int wid = tid >> 6;

    // T1: XCD swizzle, SQUARE per-XCD chunks (tile grid 32 M x 16 N; 8x8 each)
    const int xcd = blockIdx.x & 7;
    const int idx = blockIdx.x >> 3;                  // 0..63
    const int tm = ((xcd >> 1) * 8 + (idx & 7)) * 256;
    const int tn = ((xcd & 1) * 8 + (idx >> 3)) * 256;

    // staging: 8 rounds of 4KB (rounds 0-3: A rows 0-255; 4-7: B rows 0-255).
    // thread t covers (row = r*64 + (t>>2), chunk = t&3); inverse T2 swizzle on
    // the GLOBAL source: LDS[row][p] = global[row][p ^ ((row>>1)&3)].
    const int srow = tid >> 2;                         // 0..63 within round
    const int scg  = (tid & 3) ^ ((tid >> 3) & 3);     // swizzled source chunk
    const int8_t* gsrc[8];
#pragma unroll
    for (int r = 0; r < 4; ++r)
        gsrc[r] = A + (size_t)(tm + r * 64 + srow) * DIM_K + scg * 16;
#pragma unroll
    for (int r = 0; r < 4; ++r)
        gsrc[4 + r] = B + (size_t)(tn + r * 64 + srow) * DIM_K + scg * 16;
    const int dOff = tid * 16;                         // + r*4096 within buffer

    // read addressing: row i = l&15, k-chunk ch = l>>4, T2-swizzled pos
    const int i  = l & 15;
    const int ch = l >> 4;
    const int pos = (ch ^ ((i >> 1) & 3)) * 16;
    const int wm = (wid >> 1) * 128;
    const int wn = (wid & 1) * 128;
    const int aOff = (wm + i) * 64 + pos;              // + mi*1024
    const int bOff = 16384 + (wn + i) * 64 + pos;      // + ni*1024

    v4i acc[8][8] = {};

    // prologue: stage K-tiles 0,1 into bufs 0,1 (8 GLs each)
#pragma unroll
    for (int r = 0; r < 8; ++r) GL(gsrc[r], lds + r * 4096 + dOff);
#pragma unroll
    for (int r = 0; r < 8; ++r) GL(gsrc[r] + 64, lds + 32768 + r * 4096 + dOff);
    asm volatile("s_waitcnt vmcnt(8)" ::: "memory");
    __builtin_amdgcn_s_barrier();

    int cb = 0, sb = 2;
    for (int kt = 0; kt < 64; ++kt) {
        const int koff = kt * 64 + 128;                // K byte offset of tile kt+2
        const int8_t* Sc = lds + cb * 32768;
        int8_t* St = lds + sb * 32768;

        if (kt < 62) {
#pragma unroll
            for (int r = 0; r < 8; ++r) GL(gsrc[r] + koff, St + r * 4096 + dOff);
        }

        v4i af[8], bf[8];
#pragma unroll
        for (int mi = 0; mi < 8; ++mi) af[mi] = *(const v4i*)(Sc + aOff + mi * 1024);
#pragma unroll
        for (int ni = 0; ni < 8; ++ni) bf[ni] = *(const v4i*)(Sc + bOff + ni * 1024);
#pragma unroll
        for (int mi = 0; mi < 8; ++mi)
#pragma unroll
            for (int ni = 0; ni < 8; ++ni)
                acc[mi][ni] = __builtin_amdgcn_mfma_i32_16x16x64_i8(
                    af[mi], bf[ni], acc[mi][ni], 0, 0, 0);

        if (kt < 62) { asm volatile("s_waitcnt vmcnt(8)" ::: "memory"); }
        else         { asm volatile("s_waitcnt vmcnt(0)" ::: "memory"); }
        __builtin_amdgcn_s_barrier();

        cb = (cb == 2) ? 0 : cb + 1;
        sb = (sb == 2) ? 0 : sb + 1;
    }

    // epilogue: C/D layout col = l&15, row = (l>>4)*4 + j (HW-verified)
    const int gc0 = tn + wn + i;
    float scl[8], zr[8], wsm[8];
#pragma unroll
    for (int n = 0; n < 8; ++n) {
        const int gc = gc0 + n * 16;
        scl[n] = scales[gc]; zr[n] = zeros[gc]; wsm[n] = wsumf[gc];
    }
#pragma unroll
    for (int m = 0; m < 8; ++m) {
#pragma unroll
        for (int j = 0; j < 4; ++j) {
            const int gr = tm + wm + m * 16 + ch * 4 + j;
            const float ra = sA[gr], rb = sB[gr], rc = sC[gr];
            float* orow = out + (size_t)gr * DIM_N;
#pragma unroll
            for (int n = 0; n < 8; ++n)
                orow[gc0 + n * 16] =
                    scl[n] * (ra * (float)acc[m][n][j] - rb * wsm[n] - rc * zr[n]);
        }
    }
}

// ---------------------------------------------------------------------------
extern "C" void kernel_launch(void* const* d_in, const int* in_sizes, int n_in,
                              void* d_out, int out_size, void* d_ws, size_t ws_size,
                              hipStream_t stream) {
    const float* x      = (const float*)d_in[0];
    const int*   w      = (const int*)d_in[1];
    const float* scales = (const float*)d_in[2];
    const float* zeros  = (const float*)d_in[3];
    float* out = (float*)d_out;

    uint8_t* ws = (uint8_t*)d_ws;
    int8_t* q  = (int8_t*)ws;                                  // 32 MiB
    int8_t* wq = (int8_t*)(ws + (size_t)TOK_M * DIM_K);        // 16 MiB
    float* fbuf = (float*)(ws + (size_t)TOK_M * DIM_K + (size_t)DIM_N * DIM_K);
    float* sA    = fbuf;
    float* sB    = fbuf + TOK_M;
    float* sC    = fbuf + 2 * TOK_M;
    float* wsumf = fbuf + 3 * TOK_M;

    k_pack_w<<<DIM_N, 256, 0, stream>>>(w, wq, wsumf);
    k_quant<<<TOK_M, 256, 0, stream>>>(x, q, sA, sB, sC);
    k_gemm<<<512, 256, 98304, stream>>>(q, wq, sA, sB, sC, wsumf, scales, zeros, out);
}

// Round 10
// 404.676 us; speedup vs baseline: 1.2577x; 1.2577x over previous
//
#include <hip/hip_runtime.h>
#include <stdint.h>

typedef int   v4i __attribute__((ext_vector_type(4)));
typedef float v4f __attribute__((ext_vector_type(4)));

#define TOK_M 8192   // B*S = 4*2048
#define DIM_K 4096   // IN
#define DIM_N 4096   // OUT

#define GL(src, dst)                                                                   \
  __builtin_amdgcn_global_load_lds((const __attribute__((address_space(1))) void*)(src), \
                                   (__attribute__((address_space(3))) void*)(dst), 16, 0, 0)

// ---------------------------------------------------------------------------
// Kernel 1: weight int32 -> int8 pack + per-row sums (fully coalesced)
// ---------------------------------------------------------------------------
__global__ __launch_bounds__(256) void k_pack_w(const int* __restrict__ w,
                                                int8_t* __restrict__ wq,
                                                float* __restrict__ wsumf) {
    __shared__ int sred[4];
    const int row = blockIdx.x;
    const int tid = threadIdx.x;
    const int4* src = (const int4*)(w + (size_t)row * DIM_K);
    unsigned* dst = (unsigned*)(wq + (size_t)row * DIM_K);
    int sum = 0;
#pragma unroll
    for (int c = 0; c < 4; ++c) {
        int4 iv = src[c * 256 + tid];
        sum += iv.x + iv.y + iv.z + iv.w;
        unsigned p = (unsigned)(iv.x & 255) | ((unsigned)(iv.y & 255) << 8) |
                     ((unsigned)(iv.z & 255) << 16) | ((unsigned)(iv.w & 255) << 24);
        dst[c * 256 + tid] = p;
    }
#pragma unroll
    for (int off = 32; off; off >>= 1) sum += __shfl_xor(sum, off);
    if ((tid & 63) == 0) sred[tid >> 6] = sum;
    __syncthreads();
    if (tid == 0) wsumf[row] = (float)(sred[0] + sred[1] + sred[2] + sred[3]);
}

// ---------------------------------------------------------------------------
// Kernel 2: per-token dynamic quant (coalesced chunked layout)
// ---------------------------------------------------------------------------
__global__ __launch_bounds__(256) void k_quant(const float* __restrict__ x,
                                               int8_t* __restrict__ q,
                                               float* __restrict__ sA,
                                               float* __restrict__ sB,
                                               float* __restrict__ sC) {
    __shared__ float redf[8];
    __shared__ int   redi[4];
    __shared__ float bcast[2];
    const int tok = blockIdx.x;
    const int tid = threadIdx.x;
    const v4f* xr = (const v4f*)(x + (size_t)tok * DIM_K);
    v4f v[4];
    float mn = 0.0f, mx = 0.0f;
#pragma unroll
    for (int c = 0; c < 4; ++c) {
        v[c] = xr[c * 256 + tid];
#pragma unroll
        for (int j = 0; j < 4; ++j) {
            mn = fminf(mn, v[c][j]);
            mx = fmaxf(mx, v[c][j]);
        }
    }
#pragma unroll
    for (int off = 32; off; off >>= 1) {
        mn = fminf(mn, __shfl_xor(mn, off));
        mx = fmaxf(mx, __shfl_xor(mx, off));
    }
    const int wid = tid >> 6;
    if ((tid & 63) == 0) { redf[wid] = mn; redf[4 + wid] = mx; }
    __syncthreads();
    if (tid == 0) {
        float m0 = fminf(fminf(redf[0], redf[1]), fminf(redf[2], redf[3]));
        float m1 = fmaxf(fmaxf(redf[4], redf[5]), fmaxf(redf[6], redf[7]));
        float scale = fmaxf((m1 - m0) / 255.0f, 1.1920928955078125e-07f);
        float zpf = -128.0f - rintf(m0 / scale);
        zpf = fminf(fmaxf(zpf, -128.0f), 127.0f);
        bcast[0] = scale; bcast[1] = zpf;
    }
    __syncthreads();
    const float scale = bcast[0];
    const float zpf   = bcast[1];
    const float inv   = 1.0f / scale;
    int qs = 0;
    unsigned* qo = (unsigned*)(q + (size_t)tok * DIM_K);
#pragma unroll
    for (int c = 0; c < 4; ++c) {
        unsigned p = 0;
#pragma unroll
        for (int j = 0; j < 4; ++j) {
            float qf = rintf(v[c][j] * inv) + zpf;
            qf = fminf(fmaxf(qf, -128.0f), 127.0f);
            int qi = (int)qf;
            qs += qi;
            p |= ((unsigned)(qi & 255)) << (8 * j);
        }
        qo[c * 256 + tid] = p;
    }
#pragma unroll
    for (int off = 32; off; off >>= 1) qs += __shfl_xor(qs, off);
    if ((tid & 63) == 0) redi[wid] = qs;
    __syncthreads();
    if (tid == 0) {
        int qtot = redi[0] + redi[1] + redi[2] + redi[3];
        sA[tok] = scale;
        sB[tok] = scale * zpf;
        sC[tok] = scale * ((float)qtot - 4096.0f * zpf);
    }
}

// ---------------------------------------------------------------------------
// Kernel 3: int8 GEMM 256x256, 8 waves (2Mx4N), per-wave 128x64, BK=64,
// triple-buffer 96KB, FREE-FLOW tile body (no phase pins), ONE barrier +
// counted vmcnt(4) per K-tile. r3's conflict-free 16x16 pattern.
// ---------------------------------------------------------------------------
__global__ __launch_bounds__(512, 2) void k_gemm(const int8_t* __restrict__ A,
                                                 const int8_t* __restrict__ B,
                                                 const float* __restrict__ sA,
                                                 const float* __restrict__ sB,
                                                 const float* __restrict__ sC,
                                                 const float* __restrict__ wsumf,
                                                 const float* __restrict__ scales,
                                                 const float* __restrict__ zeros,
                                                 float* __restrict__ out) {
    extern __shared__ int8_t lds[];   // 3 bufs x (A 16KB + B 16KB) = 96 KB
    const int tid = threadIdx.x;
    const int l = tid & 63;
    const int wid = tid >> 6;

    // T1: XCD swizzle, SQUARE per-XCD chunks (tile grid 32 M x 16 N; 8x8 each)
    const int xcd = blockIdx.x & 7;
    const int idx = blockIdx.x >> 3;                  // 0..63
    const int tm = ((xcd >> 1) * 8 + (idx & 7)) * 256;
    const int tn = ((xcd & 1) * 8 + (idx >> 3)) * 256;

    // staging: thread -> (row=tid>>2, chunk=tid&3); inverse T2 swizzle on the
    // GLOBAL source so LDS[row][p] = global[row][p ^ ((row>>1)&3)].
    const int sr  = tid >> 2;
    const int scg = (tid & 3) ^ ((tid >> 3) & 3);
    const int8_t* aS0 = A + (size_t)(tm + sr) * DIM_K + scg * 16;
    const int8_t* aS1 = A + (size_t)(tm + 128 + sr) * DIM_K + scg * 16;
    const int8_t* bS0 = B + (size_t)(tn + sr) * DIM_K + scg * 16;
    const int8_t* bS1 = B + (size_t)(tn + 128 + sr) * DIM_K + scg * 16;
    const int dA0 = tid * 16;
    const int dA1 = 8192 + tid * 16;

    // read addressing: row i = l&15, k-chunk ch = l>>4, T2-swizzled pos
    const int i  = l & 15;
    const int ch = l >> 4;
    const int pos = (ch ^ ((i >> 1) & 3)) * 16;
    const int wm = (wid >> 2) * 128;   // 2 wave-rows
    const int wn = (wid & 3) * 64;     // 4 wave-cols
    const int aOff = (wm + i) * 64 + pos;              // + mi*1024
    const int bOff = 16384 + (wn + i) * 64 + pos;      // + ni*1024

    v4i acc[8][4] = {};

    // prologue: stage K-tiles 0,1 into bufs 0,1
    GL(aS0, lds + dA0);          GL(aS1, lds + dA1);
    GL(bS0, lds + 16384 + dA0);  GL(bS1, lds + 16384 + dA1);
    GL(aS0 + 64, lds + 32768 + dA0);          GL(aS1 + 64, lds + 32768 + dA1);
    GL(bS0 + 64, lds + 32768 + 16384 + dA0);  GL(bS1 + 64, lds + 32768 + 16384 + dA1);
    asm volatile("s_waitcnt vmcnt(4)" ::: "memory");
    __builtin_amdgcn_s_barrier();

    int cb = 0, sb = 2;
    for (int kt = 0; kt < 64; ++kt) {
        const int koff = kt * 64 + 128;                // K byte offset of tile kt+2
        const int8_t* Sc = lds + cb * 32768;
        int8_t* St = lds + sb * 32768;

        if (kt < 62) {
            GL(aS0 + koff, St + dA0);
            GL(aS1 + koff, St + dA1);
            GL(bS0 + koff, St + 16384 + dA0);
            GL(bS1 + koff, St + 16384 + dA1);
        }

        // 12 ds_read_b128 + 32 MFMA, free-flowing: compiler interleaves via
        // fine-grained lgkmcnt so one wave's MFMAs cover the other's reads.
        v4i bf0 = *(const v4i*)(Sc + bOff);
        v4i bf1 = *(const v4i*)(Sc + bOff + 1024);
        v4i bf2 = *(const v4i*)(Sc + bOff + 2048);
        v4i bf3 = *(const v4i*)(Sc + bOff + 3072);
        v4i af[8];
#pragma unroll
        for (int mi = 0; mi < 8; ++mi) af[mi] = *(const v4i*)(Sc + aOff + mi * 1024);
#pragma unroll
        for (int mi = 0; mi < 8; ++mi) {
            acc[mi][0] = __builtin_amdgcn_mfma_i32_16x16x64_i8(af[mi], bf0, acc[mi][0], 0, 0, 0);
            acc[mi][1] = __builtin_amdgcn_mfma_i32_16x16x64_i8(af[mi], bf1, acc[mi][1], 0, 0, 0);
            acc[mi][2] = __builtin_amdgcn_mfma_i32_16x16x64_i8(af[mi], bf2, acc[mi][2], 0, 0, 0);
            acc[mi][3] = __builtin_amdgcn_mfma_i32_16x16x64_i8(af[mi], bf3, acc[mi][3], 0, 0, 0);
        }

        if (kt < 62) { asm volatile("s_waitcnt vmcnt(4)" ::: "memory"); }
        else         { asm volatile("s_waitcnt vmcnt(0)" ::: "memory"); }
        __builtin_amdgcn_s_barrier();

        cb = (cb == 2) ? 0 : cb + 1;
        sb = (sb == 2) ? 0 : sb + 1;
    }

    // epilogue: C/D layout col = l&15, row = (l>>4)*4 + j (HW-verified)
    const int gc0 = tn + wn + i;
    float scl[4], zr[4], wsm[4];
#pragma unroll
    for (int n = 0; n < 4; ++n) {
        const int gc = gc0 + n * 16;
        scl[n] = scales[gc]; zr[n] = zeros[gc]; wsm[n] = wsumf[gc];
    }
#pragma unroll
    for (int m = 0; m < 8; ++m) {
#pragma unroll
        for (int j = 0; j < 4; ++j) {
            const int gr = tm + wm + m * 16 + ch * 4 + j;
            const float ra = sA[gr], rb = sB[gr], rc = sC[gr];
            float* orow = out + (size_t)gr * DIM_N;
#pragma unroll
            for (int n = 0; n < 4; ++n)
                orow[gc0 + n * 16] =
                    scl[n] * (ra * (float)acc[m][n][j] - rb * wsm[n] - rc * zr[n]);
        }
    }
}

// ---------------------------------------------------------------------------
extern "C" void kernel_launch(void* const* d_in, const int* in_sizes, int n_in,
                              void* d_out, int out_size, void* d_ws, size_t ws_size,
                              hipStream_t stream) {
    const float* x      = (const float*)d_in[0];
    const int*   w      = (const int*)d_in[1];
    const float* scales = (const float*)d_in[2];
    const float* zeros  = (const float*)d_in[3];
    float* out = (float*)d_out;

    uint8_t* ws = (uint8_t*)d_ws;
    int8_t* q  = (int8_t*)ws;                                  // 32 MiB
    int8_t* wq = (int8_t*)(ws + (size_t)TOK_M * DIM_K);        // 16 MiB
    float* fbuf = (float*)(ws + (size_t)TOK_M * DIM_K + (size_t)DIM_N * DIM_K);
    float* sA    = fbuf;
    float* sB    = fbuf + TOK_M;
    float* sC    = fbuf + 2 * TOK_M;
    float* wsumf = fbuf + 3 * TOK_M;

    k_pack_w<<<DIM_N, 256, 0, stream>>>(w, wq, wsumf);
    k_quant<<<TOK_M, 256, 0, stream>>>(x, q, sA, sB, sC);
    k_gemm<<<512, 512, 98304, stream>>>(q, wq, sA, sB, sC, wsumf, scales, zeros, out);
}